// Round 6
// baseline (530.553 us; speedup 1.0000x reference)
//
#include <hip/hip_runtime.h>
#include <cstddef>

#define F 256
#define H 256
#define NSTRUCT 1000
#define NSPEC 4
#define TM 64      // tile rows / species padding granularity
#define TPAD 264   // LDS row stride in bf16 elems

typedef __attribute__((ext_vector_type(8))) short bf16x8;
typedef __attribute__((ext_vector_type(4))) float f32x4;

__device__ __forceinline__ unsigned short f2bf(float v) {
  unsigned int u = __float_as_uint(v);
  unsigned int r = (u + 0x7FFFu + ((u >> 16) & 1u)) >> 16;  // RNE
  return (unsigned short)r;
}

__device__ __forceinline__ float bf2f(unsigned short v) {
  return __uint_as_float(((unsigned int)v) << 16);
}

__device__ __forceinline__ unsigned int pack2(float a, float b) {
  return (unsigned int)f2bf(a) | ((unsigned int)f2bf(b) << 16);
}

__device__ __forceinline__ float tanh_fast(float x) {
  x = fminf(fmaxf(x, -15.f), 15.f);
  float e = __expf(2.f * x);
  return __fdividef(e - 1.f, e + 1.f);
}

// ---------------- prep kernels ----------------

// Pack W1, W2, W2^T, W1^T into bf16 MFMA-fragment order, kk-major:
// Out[m][s][kk][jt][lane][i] = W[k][j]  (k = kk*32+(lane>>4)*8+i, j = jt*16+(lane&15))
__global__ void prep_w(const float* __restrict__ W1, const float* __restrict__ W2,
                       unsigned short* __restrict__ Out) {
  int t = blockIdx.x * 256 + threadIdx.x;
  if (t >= 4 * NSPEC * 8192) return;
  int m = t >> 15;              // 0:W1 1:W2 2:W2^T 3:W1^T
  int u = t & 32767;
  int lane = u & 63, jt = (u >> 6) & 15, kk = (u >> 10) & 7, s = u >> 13;
  int trans = (m >= 2);
  const float* In = (m == 0 || m == 3) ? W1 : W2;
  int j = jt * 16 + (lane & 15);
  int k0 = kk * 32 + (lane >> 4) * 8;
  const float* base = In + (size_t)s * F * H;
  unsigned short o[8];
  #pragma unroll
  for (int i = 0; i < 8; ++i) {
    int k = k0 + i;
    float v = trans ? base[(size_t)j * 256 + k] : base[(size_t)k * 256 + j];
    o[i] = f2bf(v);
  }
  *(ushort4*)(Out + (size_t)t * 8) = make_ushort4(o[0], o[1], o[2], o[3]);
  *(ushort4*)(Out + (size_t)t * 8 + 4) = make_ushort4(o[4], o[5], o[6], o[7]);
}

__global__ void histogram_kernel(const int* __restrict__ z, int* __restrict__ cnt, int N) {
  int i = blockIdx.x * blockDim.x + threadIdx.x;
  int lane = threadIdx.x & 63;
  int zi = (i < N) ? z[i] : -1;
  #pragma unroll
  for (int s = 0; s < NSPEC; ++s) {
    unsigned long long m = __ballot(zi == s);
    if (m != 0ull && lane == __ffsll((unsigned long long)m) - 1)
      atomicAdd(&cnt[s], __popcll(m));
  }
}

__global__ void scan_kernel(int* __restrict__ cnt, int* __restrict__ poff) {
  int acc = 0;
  for (int s = 0; s < NSPEC; ++s) {
    poff[s] = acc;
    int padded = ((cnt[s] + TM - 1) / TM) * TM;
    acc += padded;
    cnt[s] = 0;
  }
  poff[NSPEC] = acc;
}

__global__ void scatter_kernel(const int* __restrict__ z, const int* __restrict__ poff,
                               int* __restrict__ cnt, int* __restrict__ perm, int N) {
  int i = blockIdx.x * blockDim.x + threadIdx.x;
  int lane = threadIdx.x & 63;
  int zi = (i < N) ? z[i] : -1;
  #pragma unroll
  for (int s = 0; s < NSPEC; ++s) {
    unsigned long long m = __ballot(zi == s);
    if (m == 0ull) continue;
    int leader = __ffsll((unsigned long long)m) - 1;
    int base = 0;
    if (lane == leader) base = atomicAdd(&cnt[s], __popcll(m));
    base = __shfl(base, leader, 64);
    if (zi == s) {
      int rank = __popcll(m & ((1ull << lane) - 1ull));
      perm[poff[s] + base + rank] = i;
    }
  }
}

// ---------------- GEMM core ----------------

// 64x256 @ 256x256: 8 waves = 2 row-groups x 4 col-groups.
// Wave (rg,cg): rows rg*32..rg*32+31 (2 row-frags), col-tiles cg*4..cg*4+3.
__device__ __forceinline__ void gemm64(const unsigned short (*src)[TPAD],
                                       const unsigned short* __restrict__ wf,
                                       int rg, int cg, int lane, f32x4 acc[2][4]) {
  const int l15 = lane & 15, lk = lane >> 4;
  #pragma unroll
  for (int rt = 0; rt < 2; ++rt)
    #pragma unroll
    for (int q = 0; q < 4; ++q) acc[rt][q] = (f32x4){0.f, 0.f, 0.f, 0.f};
  #pragma unroll
  for (int kk = 0; kk < 8; ++kk) {
    const int kcol = kk * 32 + lk * 8;
    bf16x8 a0 = *(const bf16x8*)&src[rg * 32 + l15][kcol];
    bf16x8 a1 = *(const bf16x8*)&src[rg * 32 + 16 + l15][kcol];
    #pragma unroll
    for (int q = 0; q < 4; ++q) {
      const int jt = cg * 4 + q;
      bf16x8 b = *(const bf16x8*)(wf + ((size_t)(kk * 16 + jt) * 64 + lane) * 8);
      acc[0][q] = __builtin_amdgcn_mfma_f32_16x16x32_bf16(a0, b, acc[0][q], 0, 0, 0);
      acc[1][q] = __builtin_amdgcn_mfma_f32_16x16x32_bf16(a1, b, acc[1][q], 0, 0, 0);
    }
  }
}

// ---------------- fused MFMA MLP fwd+bwd (single LDS buffer) ----------------

__global__ __launch_bounds__(512, 6) void mlp_fused(
    const float* __restrict__ X, const int* __restrict__ smap,
    const unsigned short* __restrict__ Wf,
    const float* __restrict__ b1g, const float* __restrict__ b2g,
    const float* __restrict__ W3g, const float* __restrict__ b3g,
    const float* __restrict__ Wskipg, const float* __restrict__ bskipg,
    const int* __restrict__ perm, const int* __restrict__ poff,
    float* __restrict__ energies, unsigned short* __restrict__ nng)
{
  __shared__ __align__(16) unsigned short buf[TM][TPAD];
  __shared__ float xskp[TM][8];
  __shared__ float e_lds[TM];
  __shared__ int atom_l[TM];

  const int tid = threadIdx.x;
  const int row0 = blockIdx.x * TM;
  if (row0 >= poff[NSPEC]) return;

  int s = 0;
  #pragma unroll
  for (int q = 1; q < NSPEC; ++q)
    if (row0 >= poff[q]) s = q;

  const size_t WMAT = (size_t)NSPEC * 65536;
  const unsigned short* w1f  = Wf + (size_t)s * 65536;
  const unsigned short* w2f  = Wf + WMAT + (size_t)s * 65536;
  const unsigned short* w2tf = Wf + 2 * WMAT + (size_t)s * 65536;
  const unsigned short* w1tf = Wf + 3 * WMAT + (size_t)s * 65536;
  const float* wsk = Wskipg + s * F;

  // ---- phase 0: stage X (fp32->bf16) + skip-dot partials ----
  {
    const int lr = tid >> 3, lc = tid & 7;
    if (tid < TM) { e_lds[tid] = 0.f; atom_l[tid] = perm[row0 + tid]; }
    const int atomR = perm[row0 + lr];
    float xsk = 0.f;
    if (atomR >= 0) {
      const float4* xrow = (const float4*)(X + (size_t)atomR * F);
      #pragma unroll
      for (int jj = 0; jj < 8; ++jj) {
        const int fi = lc + jj * 8;
        float4 v = xrow[fi];
        float4 wv = ((const float4*)wsk)[fi];
        xsk += v.x * wv.x + v.y * wv.y + v.z * wv.z + v.w * wv.w;
        *(ushort4*)&buf[lr][fi * 4] =
            make_ushort4(f2bf(v.x), f2bf(v.y), f2bf(v.z), f2bf(v.w));
      }
    } else {
      #pragma unroll
      for (int jj = 0; jj < 8; ++jj)
        *(ushort4*)&buf[lr][(lc + jj * 8) * 4] = make_ushort4(0, 0, 0, 0);
    }
    xskp[lr][lc] = xsk;
  }
  __syncthreads();

  const int w = tid >> 6, lane = tid & 63;
  const int rg = w >> 2, cg = w & 3;
  const int l15 = lane & 15, lk = lane >> 4;
  f32x4 acc[2][4];
  unsigned int t1p[16];  // packed (1-h1^2): idx (q*2+rt)*2 + (r>>1)

  // ---- GEMM1: h1 = tanh(X @ W1 + b1) ----
  gemm64(buf, w1f, rg, cg, lane, acc);
  __syncthreads();  // all X reads complete
  #pragma unroll
  for (int q = 0; q < 4; ++q) {
    const int col = (cg * 4 + q) * 16 + l15;
    const float b1v = b1g[s * H + col];
    #pragma unroll
    for (int rt = 0; rt < 2; ++rt) {
      float h0 = tanh_fast(acc[rt][q][0] + b1v);
      float h1 = tanh_fast(acc[rt][q][1] + b1v);
      float h2 = tanh_fast(acc[rt][q][2] + b1v);
      float h3 = tanh_fast(acc[rt][q][3] + b1v);
      t1p[(q * 2 + rt) * 2]     = pack2(1.f - h0 * h0, 1.f - h1 * h1);
      t1p[(q * 2 + rt) * 2 + 1] = pack2(1.f - h2 * h2, 1.f - h3 * h3);
      const int rowb = rg * 32 + rt * 16 + lk * 4;
      buf[rowb + 0][col] = f2bf(h0);
      buf[rowb + 1][col] = f2bf(h1);
      buf[rowb + 2][col] = f2bf(h2);
      buf[rowb + 3][col] = f2bf(h3);
    }
  }
  __syncthreads();  // h1 visible

  // ---- GEMM2: h2 = tanh(h1 @ W2 + b2); energy partials; d2 = (1-h2^2)*W3 ----
  gemm64(buf, w2f, rg, cg, lane, acc);
  __syncthreads();  // all h1 reads complete
  {
    float ep[2][4];
    #pragma unroll
    for (int rt = 0; rt < 2; ++rt)
      #pragma unroll
      for (int r = 0; r < 4; ++r) ep[rt][r] = 0.f;
    #pragma unroll
    for (int q = 0; q < 4; ++q) {
      const int col = (cg * 4 + q) * 16 + l15;
      const float b2v = b2g[s * H + col];
      const float w3v = W3g[s * H + col];
      #pragma unroll
      for (int rt = 0; rt < 2; ++rt) {
        const int rowb = rg * 32 + rt * 16 + lk * 4;
        #pragma unroll
        for (int r = 0; r < 4; ++r) {
          float h = tanh_fast(acc[rt][q][r] + b2v);
          ep[rt][r] += h * w3v;
          buf[rowb + r][col] = f2bf((1.f - h * h) * w3v);
        }
      }
    }
    #pragma unroll
    for (int rt = 0; rt < 2; ++rt)
      #pragma unroll
      for (int r = 0; r < 4; ++r) {
        #pragma unroll
        for (int m = 1; m <= 8; m <<= 1)
          ep[rt][r] += __shfl_xor(ep[rt][r], m, 64);
      }
    if (l15 == 0) {
      #pragma unroll
      for (int rt = 0; rt < 2; ++rt)
        #pragma unroll
        for (int r = 0; r < 4; ++r)
          atomicAdd(&e_lds[rg * 32 + rt * 16 + lk * 4 + r], ep[rt][r]);
    }
  }
  __syncthreads();  // d2 visible, e_lds complete

  // ---- energies finalize ----
  if (tid < TM) {
    int atom = atom_l[tid];
    if (atom >= 0) {
      float xs = 0.f;
      #pragma unroll
      for (int q = 0; q < 8; ++q) xs += xskp[tid][q];
      atomicAdd(&energies[smap[atom]], e_lds[tid] + xs + b3g[s] + bskipg[s]);
    }
  }

  // ---- GEMM3: g1 = d2 @ W2^T; d1 = (1-h1^2)*g1 ----
  gemm64(buf, w2tf, rg, cg, lane, acc);
  __syncthreads();  // all d2 reads complete
  #pragma unroll
  for (int q = 0; q < 4; ++q) {
    const int col = (cg * 4 + q) * 16 + l15;
    #pragma unroll
    for (int rt = 0; rt < 2; ++rt) {
      unsigned int pa = t1p[(q * 2 + rt) * 2], pb = t1p[(q * 2 + rt) * 2 + 1];
      const int rowb = rg * 32 + rt * 16 + lk * 4;
      buf[rowb + 0][col] = f2bf(acc[rt][q][0] * bf2f((unsigned short)(pa & 0xffff)));
      buf[rowb + 1][col] = f2bf(acc[rt][q][1] * bf2f((unsigned short)(pa >> 16)));
      buf[rowb + 2][col] = f2bf(acc[rt][q][2] * bf2f((unsigned short)(pb & 0xffff)));
      buf[rowb + 3][col] = f2bf(acc[rt][q][3] * bf2f((unsigned short)(pb >> 16)));
    }
  }
  __syncthreads();  // d1 visible

  // ---- GEMM4: dE/dx = d1 @ W1^T + Wskip -> nng (bf16) ----
  gemm64(buf, w1tf, rg, cg, lane, acc);
  #pragma unroll
  for (int q = 0; q < 4; ++q) {
    const int col = (cg * 4 + q) * 16 + l15;
    const float wv = wsk[col];
    #pragma unroll
    for (int rt = 0; rt < 2; ++rt) {
      #pragma unroll
      for (int r = 0; r < 4; ++r) {
        int atom2 = atom_l[rg * 32 + rt * 16 + lk * 4 + r];
        if (atom2 >= 0)
          nng[(size_t)atom2 * F + col] = f2bf(acc[rt][q][r] + wv);
      }
    }
  }
}

// ---------------- forces: one wave per pair ----------------

__global__ __launch_bounds__(256) void force_kernel(
    const float* __restrict__ ptg, const int* __restrict__ gmap,
    const unsigned short* __restrict__ g, float* __restrict__ forces, int P)
{
  int w = (int)((blockIdx.x * 256 + threadIdx.x) >> 6);
  int lane = threadIdx.x & 63;
  if (w >= P) return;
  int a = gmap[w];
  ushort4 gu = *(const ushort4*)(g + (size_t)a * F + lane * 4);
  float g0 = bf2f(gu.x), g1 = bf2f(gu.y), g2 = bf2f(gu.z), g3 = bf2f(gu.w);
  const float4* gr = (const float4*)(ptg + (size_t)w * 3 * F);
  float s0, s1, s2;
  {
    float4 t = gr[0 * 64 + lane];
    s0 = t.x * g0 + t.y * g1 + t.z * g2 + t.w * g3;
    t = gr[1 * 64 + lane];
    s1 = t.x * g0 + t.y * g1 + t.z * g2 + t.w * g3;
    t = gr[2 * 64 + lane];
    s2 = t.x * g0 + t.y * g1 + t.z * g2 + t.w * g3;
  }
  #pragma unroll
  for (int off = 32; off >= 1; off >>= 1) {
    s0 += __shfl_xor(s0, off, 64);
    s1 += __shfl_xor(s1, off, 64);
    s2 += __shfl_xor(s2, off, 64);
  }
  float r = (lane == 0) ? s0 : ((lane == 1) ? s1 : s2);
  if (lane < 3) atomicAdd(&forces[(size_t)a * 3 + lane], -r);
}

// ---------------- launch ----------------

extern "C" void kernel_launch(void* const* d_in, const int* in_sizes, int n_in,
                              void* d_out, int out_size, void* d_ws, size_t ws_size,
                              hipStream_t stream) {
  const float* X     = (const float*)d_in[0];
  const int*   z     = (const int*)d_in[1];
  const int*   smap  = (const int*)d_in[2];
  const float* ptg   = (const float*)d_in[3];
  const int*   gmap  = (const int*)d_in[4];
  const float* W1    = (const float*)d_in[5];
  const float* b1    = (const float*)d_in[6];
  const float* W2    = (const float*)d_in[7];
  const float* b2    = (const float*)d_in[8];
  const float* W3    = (const float*)d_in[9];
  const float* b3    = (const float*)d_in[10];
  const float* Wskip = (const float*)d_in[11];
  const float* bskip = (const float*)d_in[12];

  const int N = in_sizes[1];
  const int P = in_sizes[4];

  char* ws = (char*)d_ws;
  int* cnt  = (int*)ws;
  int* poff = (int*)(ws + 16);
  int* perm = (int*)(ws + 64);
  size_t perm_bytes = (size_t)(N + NSPEC * TM) * sizeof(int);
  size_t off = 64 + perm_bytes;
  off = (off + 255) & ~(size_t)255;
  unsigned short* Wf = (unsigned short*)(ws + off);
  const size_t WMAT = (size_t)NSPEC * 65536;
  off += 4 * WMAT * sizeof(unsigned short);
  off = (off + 255) & ~(size_t)255;
  unsigned short* nng = (unsigned short*)(ws + off);  // N * F bf16

  float* energies = (float*)d_out;
  float* forces   = energies + NSTRUCT;

  hipMemsetAsync(d_out, 0, (size_t)out_size * sizeof(float), stream);
  hipMemsetAsync(cnt, 0, 16, stream);
  hipMemsetAsync(perm, 0xFF, perm_bytes, stream);

  prep_w<<<(4 * NSPEC * 8192 + 255) / 256, 256, 0, stream>>>(W1, W2, Wf);

  histogram_kernel<<<(N + 255) / 256, 256, 0, stream>>>(z, cnt, N);
  scan_kernel<<<1, 1, 0, stream>>>(cnt, poff);
  scatter_kernel<<<(N + 255) / 256, 256, 0, stream>>>(z, poff, cnt, perm, N);

  int mlpBlocks = (N + NSPEC * TM + TM - 1) / TM;
  mlp_fused<<<mlpBlocks, 512, 0, stream>>>(X, smap, Wf, b1, b2, W3, b3,
                                           Wskip, bskip, perm, poff,
                                           energies, nng);

  int forceBlocks = (int)(((size_t)P * 64 + 255) / 256);
  force_kernel<<<forceBlocks, 256, 0, stream>>>(ptg, gmap, nng, forces, P);
}

// Round 7
// 450.808 us; speedup vs baseline: 1.1769x; 1.1769x over previous
//
#include <hip/hip_runtime.h>
#include <cstddef>

#define F 256
#define H 256
#define NSTRUCT 1000
#define NSPEC 4
#define TM 64      // tile rows / species padding granularity
#define TPAD 264   // LDS row stride in bf16 elems

typedef __attribute__((ext_vector_type(8))) short bf16x8;
typedef __attribute__((ext_vector_type(4))) float f32x4;

__device__ __forceinline__ unsigned short f2bf(float v) {
  unsigned int u = __float_as_uint(v);
  unsigned int r = (u + 0x7FFFu + ((u >> 16) & 1u)) >> 16;  // RNE
  return (unsigned short)r;
}

__device__ __forceinline__ float bf2f(unsigned short v) {
  return __uint_as_float(((unsigned int)v) << 16);
}

__device__ __forceinline__ float tanh_fast(float x) {
  x = fminf(fmaxf(x, -15.f), 15.f);
  float e = __expf(2.f * x);
  return __fdividef(e - 1.f, e + 1.f);
}

// ---------------- prep kernels ----------------

// Pack W1, W2, W2^T, W1^T into bf16 MFMA-fragment order, kk-major:
// Out[m][s][kk][jt][lane][i] = W[k][j]  (k = kk*32+(lane>>4)*8+i, j = jt*16+(lane&15))
__global__ void prep_w(const float* __restrict__ W1, const float* __restrict__ W2,
                       unsigned short* __restrict__ Out) {
  int t = blockIdx.x * 256 + threadIdx.x;
  if (t >= 4 * NSPEC * 8192) return;
  int m = t >> 15;              // 0:W1 1:W2 2:W2^T 3:W1^T
  int u = t & 32767;
  int lane = u & 63, jt = (u >> 6) & 15, kk = (u >> 10) & 7, s = u >> 13;
  int trans = (m >= 2);
  const float* In = (m == 0 || m == 3) ? W1 : W2;
  int j = jt * 16 + (lane & 15);
  int k0 = kk * 32 + (lane >> 4) * 8;
  const float* base = In + (size_t)s * F * H;
  unsigned short o[8];
  #pragma unroll
  for (int i = 0; i < 8; ++i) {
    int k = k0 + i;
    float v = trans ? base[(size_t)j * 256 + k] : base[(size_t)k * 256 + j];
    o[i] = f2bf(v);
  }
  *(ushort4*)(Out + (size_t)t * 8) = make_ushort4(o[0], o[1], o[2], o[3]);
  *(ushort4*)(Out + (size_t)t * 8 + 4) = make_ushort4(o[4], o[5], o[6], o[7]);
}

__global__ void histogram_kernel(const int* __restrict__ z, int* __restrict__ cnt, int N) {
  int i = blockIdx.x * blockDim.x + threadIdx.x;
  int lane = threadIdx.x & 63;
  int zi = (i < N) ? z[i] : -1;
  #pragma unroll
  for (int s = 0; s < NSPEC; ++s) {
    unsigned long long m = __ballot(zi == s);
    if (m != 0ull && lane == __ffsll((unsigned long long)m) - 1)
      atomicAdd(&cnt[s], __popcll(m));
  }
}

__global__ void scan_kernel(int* __restrict__ cnt, int* __restrict__ poff) {
  int acc = 0;
  for (int s = 0; s < NSPEC; ++s) {
    poff[s] = acc;
    int padded = ((cnt[s] + TM - 1) / TM) * TM;
    acc += padded;
    cnt[s] = 0;
  }
  poff[NSPEC] = acc;
}

__global__ void scatter_kernel(const int* __restrict__ z, const int* __restrict__ poff,
                               int* __restrict__ cnt, int* __restrict__ perm, int N) {
  int i = blockIdx.x * blockDim.x + threadIdx.x;
  int lane = threadIdx.x & 63;
  int zi = (i < N) ? z[i] : -1;
  #pragma unroll
  for (int s = 0; s < NSPEC; ++s) {
    unsigned long long m = __ballot(zi == s);
    if (m == 0ull) continue;
    int leader = __ffsll((unsigned long long)m) - 1;
    int base = 0;
    if (lane == leader) base = atomicAdd(&cnt[s], __popcll(m));
    base = __shfl(base, leader, 64);
    if (zi == s) {
      int rank = __popcll(m & ((1ull << lane) - 1ull));
      perm[poff[s] + base + rank] = i;
    }
  }
}

// ---------------- GEMM core ----------------

// 64x256 @ 256x256: 8 waves = 2 row-groups x 4 col-groups.
// Wave (rg,cg): rows rg*32..rg*32+31 (2 row-frags), col-tiles cg*4..cg*4+3.
__device__ __forceinline__ void gemm64(const unsigned short (*src)[TPAD],
                                       const unsigned short* __restrict__ wf,
                                       int rg, int cg, int lane, f32x4 acc[2][4]) {
  const int l15 = lane & 15, lk = lane >> 4;
  #pragma unroll
  for (int rt = 0; rt < 2; ++rt)
    #pragma unroll
    for (int q = 0; q < 4; ++q) acc[rt][q] = (f32x4){0.f, 0.f, 0.f, 0.f};
  #pragma unroll
  for (int kk = 0; kk < 8; ++kk) {
    const int kcol = kk * 32 + lk * 8;
    bf16x8 a0 = *(const bf16x8*)&src[rg * 32 + l15][kcol];
    bf16x8 a1 = *(const bf16x8*)&src[rg * 32 + 16 + l15][kcol];
    #pragma unroll
    for (int q = 0; q < 4; ++q) {
      const int jt = cg * 4 + q;
      bf16x8 b = *(const bf16x8*)(wf + ((size_t)(kk * 16 + jt) * 64 + lane) * 8);
      acc[0][q] = __builtin_amdgcn_mfma_f32_16x16x32_bf16(a0, b, acc[0][q], 0, 0, 0);
      acc[1][q] = __builtin_amdgcn_mfma_f32_16x16x32_bf16(a1, b, acc[1][q], 0, 0, 0);
    }
  }
}

// ---------------- fused MFMA MLP fwd+bwd (round-3 structure, rg/cg mapping) ----------------

__global__ __launch_bounds__(512, 4) void mlp_fused(
    const float* __restrict__ X, const int* __restrict__ smap,
    const unsigned short* __restrict__ Wf,
    const float* __restrict__ b1g, const float* __restrict__ b2g,
    const float* __restrict__ W3g, const float* __restrict__ b3g,
    const float* __restrict__ Wskipg, const float* __restrict__ bskipg,
    const int* __restrict__ perm, const int* __restrict__ poff,
    float* __restrict__ energies, unsigned short* __restrict__ nng)
{
  __shared__ __align__(16) unsigned short bufA[TM][TPAD];
  __shared__ __align__(16) unsigned short bufB[TM][TPAD];
  __shared__ float xskp[TM][8];
  __shared__ float e_lds[TM];
  __shared__ int atom_l[TM];

  const int tid = threadIdx.x;
  const int row0 = blockIdx.x * TM;
  if (row0 >= poff[NSPEC]) return;

  int s = 0;
  #pragma unroll
  for (int q = 1; q < NSPEC; ++q)
    if (row0 >= poff[q]) s = q;

  const size_t WMAT = (size_t)NSPEC * 65536;
  const unsigned short* w1f  = Wf + (size_t)s * 65536;
  const unsigned short* w2f  = Wf + WMAT + (size_t)s * 65536;
  const unsigned short* w2tf = Wf + 2 * WMAT + (size_t)s * 65536;
  const unsigned short* w1tf = Wf + 3 * WMAT + (size_t)s * 65536;
  const float* wsk = Wskipg + s * F;

  // ---- phase 0: stage X (fp32->bf16) + skip-dot partials ----
  {
    const int lr = tid >> 3, lc = tid & 7;
    if (tid < TM) { e_lds[tid] = 0.f; atom_l[tid] = perm[row0 + tid]; }
    const int atomR = perm[row0 + lr];
    float xsk = 0.f;
    if (atomR >= 0) {
      const float4* xrow = (const float4*)(X + (size_t)atomR * F);
      #pragma unroll
      for (int jj = 0; jj < 8; ++jj) {
        const int fi = lc + jj * 8;
        float4 v = xrow[fi];
        float4 wv = ((const float4*)wsk)[fi];
        xsk += v.x * wv.x + v.y * wv.y + v.z * wv.z + v.w * wv.w;
        *(ushort4*)&bufA[lr][fi * 4] =
            make_ushort4(f2bf(v.x), f2bf(v.y), f2bf(v.z), f2bf(v.w));
      }
    } else {
      #pragma unroll
      for (int jj = 0; jj < 8; ++jj)
        *(ushort4*)&bufA[lr][(lc + jj * 8) * 4] = make_ushort4(0, 0, 0, 0);
    }
    xskp[lr][lc] = xsk;
  }
  __syncthreads();

  const int w = tid >> 6, lane = tid & 63;
  const int rg = w >> 2, cg = w & 3;
  const int l15 = lane & 15, lk = lane >> 4;
  f32x4 acc[2][4];

  // ---- GEMM1: h1 = tanh(X @ W1 + b1) -> bufB ----
  gemm64(bufA, w1f, rg, cg, lane, acc);
  #pragma unroll
  for (int q = 0; q < 4; ++q) {
    const int col = (cg * 4 + q) * 16 + l15;
    const float b1v = b1g[s * H + col];
    #pragma unroll
    for (int rt = 0; rt < 2; ++rt) {
      const int rowb = rg * 32 + rt * 16 + lk * 4;
      #pragma unroll
      for (int r = 0; r < 4; ++r)
        bufB[rowb + r][col] = f2bf(tanh_fast(acc[rt][q][r] + b1v));
    }
  }
  __syncthreads();

  // ---- GEMM2: h2 = tanh(h1 @ W2 + b2); energy partials; d2 = (1-h2^2)*W3 -> bufA ----
  gemm64(bufB, w2f, rg, cg, lane, acc);
  {
    float ep[2][4];
    #pragma unroll
    for (int rt = 0; rt < 2; ++rt)
      #pragma unroll
      for (int r = 0; r < 4; ++r) ep[rt][r] = 0.f;
    #pragma unroll
    for (int q = 0; q < 4; ++q) {
      const int col = (cg * 4 + q) * 16 + l15;
      const float b2v = b2g[s * H + col];
      const float w3v = W3g[s * H + col];
      #pragma unroll
      for (int rt = 0; rt < 2; ++rt) {
        const int rowb = rg * 32 + rt * 16 + lk * 4;
        #pragma unroll
        for (int r = 0; r < 4; ++r) {
          float h = tanh_fast(acc[rt][q][r] + b2v);
          ep[rt][r] += h * w3v;
          bufA[rowb + r][col] = f2bf((1.f - h * h) * w3v);
        }
      }
    }
    #pragma unroll
    for (int rt = 0; rt < 2; ++rt)
      #pragma unroll
      for (int r = 0; r < 4; ++r) {
        #pragma unroll
        for (int m = 1; m <= 8; m <<= 1)
          ep[rt][r] += __shfl_xor(ep[rt][r], m, 64);
      }
    if (l15 == 0) {
      #pragma unroll
      for (int rt = 0; rt < 2; ++rt)
        #pragma unroll
        for (int r = 0; r < 4; ++r)
          atomicAdd(&e_lds[rg * 32 + rt * 16 + lk * 4 + r], ep[rt][r]);
    }
  }
  __syncthreads();

  // ---- energies finalize ----
  if (tid < TM) {
    int atom = atom_l[tid];
    if (atom >= 0) {
      float xs = 0.f;
      #pragma unroll
      for (int q = 0; q < 8; ++q) xs += xskp[tid][q];
      atomicAdd(&energies[smap[atom]], e_lds[tid] + xs + b3g[s] + bskipg[s]);
    }
  }

  // ---- GEMM3: g1 = d2 @ W2^T; d1 = (1-h1^2)*g1 -> bufB (in-place h1 RMW) ----
  gemm64(bufA, w2tf, rg, cg, lane, acc);
  #pragma unroll
  for (int q = 0; q < 4; ++q) {
    const int col = (cg * 4 + q) * 16 + l15;
    #pragma unroll
    for (int rt = 0; rt < 2; ++rt) {
      const int rowb = rg * 32 + rt * 16 + lk * 4;
      #pragma unroll
      for (int r = 0; r < 4; ++r) {
        float h = bf2f(bufB[rowb + r][col]);
        bufB[rowb + r][col] = f2bf((1.f - h * h) * acc[rt][q][r]);
      }
    }
  }
  __syncthreads();

  // ---- GEMM4: dE/dx = d1 @ W1^T + Wskip -> nng (bf16) ----
  gemm64(bufB, w1tf, rg, cg, lane, acc);
  #pragma unroll
  for (int q = 0; q < 4; ++q) {
    const int col = (cg * 4 + q) * 16 + l15;
    const float wv = wsk[col];
    #pragma unroll
    for (int rt = 0; rt < 2; ++rt) {
      #pragma unroll
      for (int r = 0; r < 4; ++r) {
        int atom2 = atom_l[rg * 32 + rt * 16 + lk * 4 + r];
        if (atom2 >= 0)
          nng[(size_t)atom2 * F + col] = f2bf(acc[rt][q][r] + wv);
      }
    }
  }
}

// ---------------- forces: 4 pairs per wave (16 lanes each) ----------------

__global__ __launch_bounds__(256) void force_kernel(
    const float* __restrict__ ptg, const int* __restrict__ gmap,
    const unsigned short* __restrict__ g, float* __restrict__ forces, int P)
{
  const int wave = (int)((blockIdx.x * 256 + threadIdx.x) >> 6);
  const int lane = threadIdx.x & 63;
  const int grp = lane >> 4, l = lane & 15;
  const int p = wave * 4 + grp;
  if (p >= P) return;
  const int a = gmap[p];

  // this lane's 16 contiguous features: f = l*16 .. l*16+15
  const unsigned short* grow = g + (size_t)a * F + l * 16;
  bf16x8 ga = *(const bf16x8*)grow;
  bf16x8 gb = *(const bf16x8*)(grow + 8);
  float gv[16];
  #pragma unroll
  for (int i = 0; i < 8; ++i) {
    gv[i]     = bf2f((unsigned short)ga[i]);
    gv[8 + i] = bf2f((unsigned short)gb[i]);
  }

  const float* pr = ptg + (size_t)p * 3 * F;
  float sc[3];
  #pragma unroll
  for (int c = 0; c < 3; ++c) {
    float s = 0.f;
    #pragma unroll
    for (int j = 0; j < 4; ++j) {
      float4 t = *(const float4*)(pr + c * F + l * 16 + j * 4);
      s += t.x * gv[j * 4] + t.y * gv[j * 4 + 1]
         + t.z * gv[j * 4 + 2] + t.w * gv[j * 4 + 3];
    }
    sc[c] = s;
  }
  #pragma unroll
  for (int off = 1; off <= 8; off <<= 1) {
    sc[0] += __shfl_xor(sc[0], off, 64);
    sc[1] += __shfl_xor(sc[1], off, 64);
    sc[2] += __shfl_xor(sc[2], off, 64);
  }
  float r = (l == 0) ? sc[0] : ((l == 1) ? sc[1] : sc[2]);
  if (l < 3) atomicAdd(&forces[(size_t)a * 3 + l], -r);
}

// ---------------- launch ----------------

extern "C" void kernel_launch(void* const* d_in, const int* in_sizes, int n_in,
                              void* d_out, int out_size, void* d_ws, size_t ws_size,
                              hipStream_t stream) {
  const float* X     = (const float*)d_in[0];
  const int*   z     = (const int*)d_in[1];
  const int*   smap  = (const int*)d_in[2];
  const float* ptg   = (const float*)d_in[3];
  const int*   gmap  = (const int*)d_in[4];
  const float* W1    = (const float*)d_in[5];
  const float* b1    = (const float*)d_in[6];
  const float* W2    = (const float*)d_in[7];
  const float* b2    = (const float*)d_in[8];
  const float* W3    = (const float*)d_in[9];
  const float* b3    = (const float*)d_in[10];
  const float* Wskip = (const float*)d_in[11];
  const float* bskip = (const float*)d_in[12];

  const int N = in_sizes[1];
  const int P = in_sizes[4];

  char* ws = (char*)d_ws;
  int* cnt  = (int*)ws;
  int* poff = (int*)(ws + 16);
  int* perm = (int*)(ws + 64);
  size_t perm_bytes = (size_t)(N + NSPEC * TM) * sizeof(int);
  size_t off = 64 + perm_bytes;
  off = (off + 255) & ~(size_t)255;
  unsigned short* Wf = (unsigned short*)(ws + off);
  const size_t WMAT = (size_t)NSPEC * 65536;
  off += 4 * WMAT * sizeof(unsigned short);
  off = (off + 255) & ~(size_t)255;
  unsigned short* nng = (unsigned short*)(ws + off);  // N * F bf16

  float* energies = (float*)d_out;
  float* forces   = energies + NSTRUCT;

  hipMemsetAsync(d_out, 0, (size_t)out_size * sizeof(float), stream);
  hipMemsetAsync(cnt, 0, 16, stream);
  hipMemsetAsync(perm, 0xFF, perm_bytes, stream);

  prep_w<<<(4 * NSPEC * 8192 + 255) / 256, 256, 0, stream>>>(W1, W2, Wf);

  histogram_kernel<<<(N + 255) / 256, 256, 0, stream>>>(z, cnt, N);
  scan_kernel<<<1, 1, 0, stream>>>(cnt, poff);
  scatter_kernel<<<(N + 255) / 256, 256, 0, stream>>>(z, poff, cnt, perm, N);

  int mlpBlocks = (N + NSPEC * TM + TM - 1) / TM;
  mlp_fused<<<mlpBlocks, 512, 0, stream>>>(X, smap, Wf, b1, b2, W3, b3,
                                           Wskip, bskip, perm, poff,
                                           energies, nng);

  int forceBlocks = (P + 15) / 16;
  force_kernel<<<forceBlocks, 256, 0, stream>>>(ptg, gmap, nng, forces, P);
}

// Round 8
// 399.122 us; speedup vs baseline: 1.3293x; 1.1295x over previous
//
#include <hip/hip_runtime.h>
#include <cstddef>

#define F 256
#define H 256
#define NSTRUCT 1000
#define NSPEC 4
#define TM 64      // tile rows / species padding granularity
#define TPAD 264   // LDS row stride in bf16 elems

typedef __attribute__((ext_vector_type(8))) short bf16x8;
typedef __attribute__((ext_vector_type(4))) float f32x4;

__device__ __forceinline__ unsigned short f2bf(float v) {
  unsigned int u = __float_as_uint(v);
  unsigned int r = (u + 0x7FFFu + ((u >> 16) & 1u)) >> 16;  // RNE
  return (unsigned short)r;
}

__device__ __forceinline__ float bf2f(unsigned short v) {
  return __uint_as_float(((unsigned int)v) << 16);
}

__device__ __forceinline__ float tanh_fast(float x) {
  x = fminf(fmaxf(x, -15.f), 15.f);
  float e = __expf(2.f * x);
  return __fdividef(e - 1.f, e + 1.f);
}

// ---------------- prep kernels ----------------

// Pack W1, W2, W2^T, W1^T into bf16 MFMA-fragment order, kk-major:
// Out[m][s][kk][jt][lane][i] = W[k][j]  (k = kk*32+(lane>>4)*8+i, j = jt*16+(lane&15))
__global__ void prep_w(const float* __restrict__ W1, const float* __restrict__ W2,
                       unsigned short* __restrict__ Out) {
  int t = blockIdx.x * 256 + threadIdx.x;
  if (t >= 4 * NSPEC * 8192) return;
  int m = t >> 15;              // 0:W1 1:W2 2:W2^T 3:W1^T
  int u = t & 32767;
  int lane = u & 63, jt = (u >> 6) & 15, kk = (u >> 10) & 7, s = u >> 13;
  int trans = (m >= 2);
  const float* In = (m == 0 || m == 3) ? W1 : W2;
  int j = jt * 16 + (lane & 15);
  int k0 = kk * 32 + (lane >> 4) * 8;
  const float* base = In + (size_t)s * F * H;
  unsigned short o[8];
  #pragma unroll
  for (int i = 0; i < 8; ++i) {
    int k = k0 + i;
    float v = trans ? base[(size_t)j * 256 + k] : base[(size_t)k * 256 + j];
    o[i] = f2bf(v);
  }
  *(ushort4*)(Out + (size_t)t * 8) = make_ushort4(o[0], o[1], o[2], o[3]);
  *(ushort4*)(Out + (size_t)t * 8 + 4) = make_ushort4(o[4], o[5], o[6], o[7]);
}

__global__ void histogram_kernel(const int* __restrict__ z, int* __restrict__ cnt, int N) {
  int i = blockIdx.x * blockDim.x + threadIdx.x;
  int lane = threadIdx.x & 63;
  int zi = (i < N) ? z[i] : -1;
  #pragma unroll
  for (int s = 0; s < NSPEC; ++s) {
    unsigned long long m = __ballot(zi == s);
    if (m != 0ull && lane == __ffsll((unsigned long long)m) - 1)
      atomicAdd(&cnt[s], __popcll(m));
  }
}

__global__ void scan_kernel(int* __restrict__ cnt, int* __restrict__ poff) {
  int acc = 0;
  for (int s = 0; s < NSPEC; ++s) {
    poff[s] = acc;
    int padded = ((cnt[s] + TM - 1) / TM) * TM;
    acc += padded;
    cnt[s] = 0;
  }
  poff[NSPEC] = acc;
}

__global__ void scatter_kernel(const int* __restrict__ z, const int* __restrict__ poff,
                               int* __restrict__ cnt, int* __restrict__ perm, int N) {
  int i = blockIdx.x * blockDim.x + threadIdx.x;
  int lane = threadIdx.x & 63;
  int zi = (i < N) ? z[i] : -1;
  #pragma unroll
  for (int s = 0; s < NSPEC; ++s) {
    unsigned long long m = __ballot(zi == s);
    if (m == 0ull) continue;
    int leader = __ffsll((unsigned long long)m) - 1;
    int base = 0;
    if (lane == leader) base = atomicAdd(&cnt[s], __popcll(m));
    base = __shfl(base, leader, 64);
    if (zi == s) {
      int rank = __popcll(m & ((1ull << lane) - 1ull));
      perm[poff[s] + base + rank] = i;
    }
  }
}

// ---------------- GEMM core (round-3 mapping: wave w -> col-tiles {2w,2w+1}, all 4 row-frags) ----------------

__device__ __forceinline__ void gemm64(const unsigned short (*src)[TPAD],
                                       const unsigned short* __restrict__ wf,
                                       int w, int lane, f32x4 acc[4][2]) {
  const int l15 = lane & 15, lk = lane >> 4;
  #pragma unroll
  for (int rt = 0; rt < 4; ++rt)
    #pragma unroll
    for (int q = 0; q < 2; ++q) acc[rt][q] = (f32x4){0.f, 0.f, 0.f, 0.f};
  #pragma unroll
  for (int kk = 0; kk < 8; ++kk) {
    const int kcol = kk * 32 + lk * 8;
    bf16x8 a0 = *(const bf16x8*)&src[l15][kcol];
    bf16x8 a1 = *(const bf16x8*)&src[16 + l15][kcol];
    bf16x8 a2 = *(const bf16x8*)&src[32 + l15][kcol];
    bf16x8 a3 = *(const bf16x8*)&src[48 + l15][kcol];
    #pragma unroll
    for (int q = 0; q < 2; ++q) {
      const int jt = w * 2 + q;
      bf16x8 b = *(const bf16x8*)(wf + ((size_t)(kk * 16 + jt) * 64 + lane) * 8);
      acc[0][q] = __builtin_amdgcn_mfma_f32_16x16x32_bf16(a0, b, acc[0][q], 0, 0, 0);
      acc[1][q] = __builtin_amdgcn_mfma_f32_16x16x32_bf16(a1, b, acc[1][q], 0, 0, 0);
      acc[2][q] = __builtin_amdgcn_mfma_f32_16x16x32_bf16(a2, b, acc[2][q], 0, 0, 0);
      acc[3][q] = __builtin_amdgcn_mfma_f32_16x16x32_bf16(a3, b, acc[3][q], 0, 0, 0);
    }
  }
}

// ---------------- fused MFMA MLP fwd+bwd (round-3 structure) ----------------

__global__ __launch_bounds__(512, 4) void mlp_fused(
    const float* __restrict__ X, const int* __restrict__ smap,
    const unsigned short* __restrict__ Wf,
    const float* __restrict__ b1g, const float* __restrict__ b2g,
    const float* __restrict__ W3g, const float* __restrict__ b3g,
    const float* __restrict__ Wskipg, const float* __restrict__ bskipg,
    const int* __restrict__ perm, const int* __restrict__ poff,
    float* __restrict__ energies, unsigned short* __restrict__ nng)
{
  __shared__ __align__(16) unsigned short bufA[TM][TPAD];
  __shared__ __align__(16) unsigned short bufB[TM][TPAD];
  __shared__ float xskp[TM][8];
  __shared__ float e_lds[TM];
  __shared__ int atom_l[TM];

  const int tid = threadIdx.x;
  const int row0 = blockIdx.x * TM;
  if (row0 >= poff[NSPEC]) return;

  int s = 0;
  #pragma unroll
  for (int q = 1; q < NSPEC; ++q)
    if (row0 >= poff[q]) s = q;

  const size_t WMAT = (size_t)NSPEC * 65536;
  const unsigned short* w1f  = Wf + (size_t)s * 65536;
  const unsigned short* w2f  = Wf + WMAT + (size_t)s * 65536;
  const unsigned short* w2tf = Wf + 2 * WMAT + (size_t)s * 65536;
  const unsigned short* w1tf = Wf + 3 * WMAT + (size_t)s * 65536;
  const float* wsk = Wskipg + s * F;

  // ---- phase 0: stage X (fp32->bf16, nontemporal) + skip-dot partials ----
  {
    const int lr = tid >> 3, lc = tid & 7;
    if (tid < TM) { e_lds[tid] = 0.f; atom_l[tid] = perm[row0 + tid]; }
    const int atomR = perm[row0 + lr];
    float xsk = 0.f;
    if (atomR >= 0) {
      const f32x4* xrow = (const f32x4*)(X + (size_t)atomR * F);
      #pragma unroll
      for (int jj = 0; jj < 8; ++jj) {
        const int fi = lc + jj * 8;
        f32x4 v = __builtin_nontemporal_load(xrow + fi);
        float4 wv = ((const float4*)wsk)[fi];
        xsk += v[0] * wv.x + v[1] * wv.y + v[2] * wv.z + v[3] * wv.w;
        *(ushort4*)&bufA[lr][fi * 4] =
            make_ushort4(f2bf(v[0]), f2bf(v[1]), f2bf(v[2]), f2bf(v[3]));
      }
    } else {
      #pragma unroll
      for (int jj = 0; jj < 8; ++jj)
        *(ushort4*)&bufA[lr][(lc + jj * 8) * 4] = make_ushort4(0, 0, 0, 0);
    }
    xskp[lr][lc] = xsk;
  }
  __syncthreads();

  const int w = tid >> 6, lane = tid & 63;
  const int l15 = lane & 15, lk = lane >> 4;
  f32x4 acc[4][2];

  // ---- GEMM1: h1 = tanh(X @ W1 + b1) -> bufB ----
  gemm64(bufA, w1f, w, lane, acc);
  #pragma unroll
  for (int q = 0; q < 2; ++q) {
    const int col = (w * 2 + q) * 16 + l15;
    const float b1v = b1g[s * H + col];
    #pragma unroll
    for (int rt = 0; rt < 4; ++rt) {
      const int rowb = rt * 16 + lk * 4;
      #pragma unroll
      for (int r = 0; r < 4; ++r)
        bufB[rowb + r][col] = f2bf(tanh_fast(acc[rt][q][r] + b1v));
    }
  }
  __syncthreads();

  // ---- GEMM2: h2 = tanh(h1 @ W2 + b2); energy partials; d2 = (1-h2^2)*W3 -> bufA ----
  gemm64(bufB, w2f, w, lane, acc);
  {
    float ep[4][4];
    #pragma unroll
    for (int rt = 0; rt < 4; ++rt)
      #pragma unroll
      for (int r = 0; r < 4; ++r) ep[rt][r] = 0.f;
    #pragma unroll
    for (int q = 0; q < 2; ++q) {
      const int col = (w * 2 + q) * 16 + l15;
      const float b2v = b2g[s * H + col];
      const float w3v = W3g[s * H + col];
      #pragma unroll
      for (int rt = 0; rt < 4; ++rt) {
        const int rowb = rt * 16 + lk * 4;
        #pragma unroll
        for (int r = 0; r < 4; ++r) {
          float h = tanh_fast(acc[rt][q][r] + b2v);
          ep[rt][r] += h * w3v;
          bufA[rowb + r][col] = f2bf((1.f - h * h) * w3v);
        }
      }
    }
    #pragma unroll
    for (int rt = 0; rt < 4; ++rt)
      #pragma unroll
      for (int r = 0; r < 4; ++r) {
        #pragma unroll
        for (int m = 1; m <= 8; m <<= 1)
          ep[rt][r] += __shfl_xor(ep[rt][r], m, 64);
      }
    if (l15 == 0) {
      #pragma unroll
      for (int rt = 0; rt < 4; ++rt)
        #pragma unroll
        for (int r = 0; r < 4; ++r)
          atomicAdd(&e_lds[rt * 16 + lk * 4 + r], ep[rt][r]);
    }
  }
  __syncthreads();

  // ---- energies finalize ----
  if (tid < TM) {
    int atom = atom_l[tid];
    if (atom >= 0) {
      float xs = 0.f;
      #pragma unroll
      for (int q = 0; q < 8; ++q) xs += xskp[tid][q];
      atomicAdd(&energies[smap[atom]], e_lds[tid] + xs + b3g[s] + bskipg[s]);
    }
  }

  // ---- GEMM3: g1 = d2 @ W2^T; d1 = (1-h1^2)*g1 -> bufB (in-place h1 RMW) ----
  gemm64(bufA, w2tf, w, lane, acc);
  #pragma unroll
  for (int q = 0; q < 2; ++q) {
    const int col = (w * 2 + q) * 16 + l15;
    #pragma unroll
    for (int rt = 0; rt < 4; ++rt) {
      const int rowb = rt * 16 + lk * 4;
      #pragma unroll
      for (int r = 0; r < 4; ++r) {
        float h = bf2f(bufB[rowb + r][col]);
        bufB[rowb + r][col] = f2bf((1.f - h * h) * acc[rt][q][r]);
      }
    }
  }
  __syncthreads();

  // ---- GEMM4: dE/dx = d1 @ W1^T + Wskip -> nng (bf16) ----
  gemm64(bufB, w1tf, w, lane, acc);
  #pragma unroll
  for (int q = 0; q < 2; ++q) {
    const int col = (w * 2 + q) * 16 + l15;
    const float wv = wsk[col];
    #pragma unroll
    for (int rt = 0; rt < 4; ++rt) {
      #pragma unroll
      for (int r = 0; r < 4; ++r) {
        int atom2 = atom_l[rt * 16 + lk * 4 + r];
        if (atom2 >= 0)
          nng[(size_t)atom2 * F + col] = f2bf(acc[rt][q][r] + wv);
      }
    }
  }
}

// ---------------- forces: one wave per pair, nontemporal ptg stream ----------------

__global__ __launch_bounds__(256) void force_kernel(
    const float* __restrict__ ptg, const int* __restrict__ gmap,
    const unsigned short* __restrict__ g, float* __restrict__ forces, int P)
{
  int w = (int)((blockIdx.x * 256 + threadIdx.x) >> 6);
  int lane = threadIdx.x & 63;
  if (w >= P) return;
  int a = gmap[w];
  ushort4 gu = *(const ushort4*)(g + (size_t)a * F + lane * 4);
  float g0 = bf2f(gu.x), g1 = bf2f(gu.y), g2 = bf2f(gu.z), g3 = bf2f(gu.w);
  const f32x4* gr = (const f32x4*)(ptg + (size_t)w * 3 * F);
  f32x4 t0 = __builtin_nontemporal_load(gr + 0 * 64 + lane);
  f32x4 t1 = __builtin_nontemporal_load(gr + 1 * 64 + lane);
  f32x4 t2 = __builtin_nontemporal_load(gr + 2 * 64 + lane);
  float s0 = t0[0] * g0 + t0[1] * g1 + t0[2] * g2 + t0[3] * g3;
  float s1 = t1[0] * g0 + t1[1] * g1 + t1[2] * g2 + t1[3] * g3;
  float s2 = t2[0] * g0 + t2[1] * g1 + t2[2] * g2 + t2[3] * g3;
  #pragma unroll
  for (int off = 32; off >= 1; off >>= 1) {
    s0 += __shfl_xor(s0, off, 64);
    s1 += __shfl_xor(s1, off, 64);
    s2 += __shfl_xor(s2, off, 64);
  }
  float r = (lane == 0) ? s0 : ((lane == 1) ? s1 : s2);
  if (lane < 3) atomicAdd(&forces[(size_t)a * 3 + lane], -r);
}

// ---------------- launch ----------------

extern "C" void kernel_launch(void* const* d_in, const int* in_sizes, int n_in,
                              void* d_out, int out_size, void* d_ws, size_t ws_size,
                              hipStream_t stream) {
  const float* X     = (const float*)d_in[0];
  const int*   z     = (const int*)d_in[1];
  const int*   smap  = (const int*)d_in[2];
  const float* ptg   = (const float*)d_in[3];
  const int*   gmap  = (const int*)d_in[4];
  const float* W1    = (const float*)d_in[5];
  const float* b1    = (const float*)d_in[6];
  const float* W2    = (const float*)d_in[7];
  const float* b2    = (const float*)d_in[8];
  const float* W3    = (const float*)d_in[9];
  const float* b3    = (const float*)d_in[10];
  const float* Wskip = (const float*)d_in[11];
  const float* bskip = (const float*)d_in[12];

  const int N = in_sizes[1];
  const int P = in_sizes[4];

  char* ws = (char*)d_ws;
  int* cnt  = (int*)ws;
  int* poff = (int*)(ws + 16);
  int* perm = (int*)(ws + 64);
  size_t perm_bytes = (size_t)(N + NSPEC * TM) * sizeof(int);
  size_t off = 64 + perm_bytes;
  off = (off + 255) & ~(size_t)255;
  unsigned short* Wf = (unsigned short*)(ws + off);
  const size_t WMAT = (size_t)NSPEC * 65536;
  off += 4 * WMAT * sizeof(unsigned short);
  off = (off + 255) & ~(size_t)255;
  unsigned short* nng = (unsigned short*)(ws + off);  // N * F bf16

  float* energies = (float*)d_out;
  float* forces   = energies + NSTRUCT;

  hipMemsetAsync(d_out, 0, (size_t)out_size * sizeof(float), stream);
  hipMemsetAsync(cnt, 0, 16, stream);
  hipMemsetAsync(perm, 0xFF, perm_bytes, stream);

  prep_w<<<(4 * NSPEC * 8192 + 255) / 256, 256, 0, stream>>>(W1, W2, Wf);

  histogram_kernel<<<(N + 255) / 256, 256, 0, stream>>>(z, cnt, N);
  scan_kernel<<<1, 1, 0, stream>>>(cnt, poff);
  scatter_kernel<<<(N + 255) / 256, 256, 0, stream>>>(z, poff, cnt, perm, N);

  int mlpBlocks = (N + NSPEC * TM + TM - 1) / TM;
  mlp_fused<<<mlpBlocks, 512, 0, stream>>>(X, smap, Wf, b1, b2, W3, b3,
                                           Wskip, bskip, perm, poff,
                                           energies, nng);

  int forceBlocks = (int)(((size_t)P * 64 + 255) / 256);
  force_kernel<<<forceBlocks, 256, 0, stream>>>(ptg, gmap, nng, forces, P);
}